// Round 12
// baseline (134.991 us; speedup 1.0000x reference)
//
#include <hip/hip_runtime.h>

// SpecialSpmm: out[i] = sum_{e: row_e == i} values[e] * b[col_e]
// N = 100000, E = 1600000, D = 128.
//
// Pipeline (zero global atomics on the data path):
//   K01 k01_fused:  per CH-edge chunk: LDS bucket histogram (int4-vectorized)
//                   -> cnt16[c][k], PLUS grid-strided f32->bf16 cast of b
//                   (nt loads of b: single-touch, keep IC for bb)
//   K2  k2_merged:  wave-per-bucket prefix over chunks (cnt16 -> lofs) +
//                   totals; LAST block (device-scope done counter) performs
//                   the exclusive scan of totals -> boff (k2b folded in)
//   K3  k3_scatter: per chunk (XCD-chunked remap): cur[k]=boff[k]+lofs[c][k],
//                   int4/float4-vectorized edge loads (nt for cols/values),
//                   write records to final cv slot (LDS cursors only)
//   K4  k4_reg_bf16: per bucket: cv segment read ONCE (nt) into registers,
//                   LDS hist, wave-scan, reg->LDS counting scatter, bf16
//                   register gather (16 grp x 4 rows x bf16x8/lane),
//                   nt coalesced out stores (single-touch).
//
// d_in[0] = values (E f32), d_in[1] = b (N*D f32),
// d_in[2] = indices (2*E i32: rows then cols), d_in[3] = n (1 i32).

#define D_DIM    128
#define RPB      64                    // rows per bucket
#define COLBITS  17                    // N <= 131072
#define COLMASK  ((1 << COLBITS) - 1)
#define NCMAX    512                   // max chunks supported by k2 (8/lane)
#define NBMAX    1600                  // max buckets (N <= 102400)
#define CAP      2048                  // LDS sorted capacity (records)
#define NXCD     8

typedef int   i32x4 __attribute__((ext_vector_type(4)));
typedef float f32x4 __attribute__((ext_vector_type(4)));
typedef unsigned int u32x4 __attribute__((ext_vector_type(4)));

__device__ __forceinline__ unsigned bfr_rne(float f) {
    unsigned u = __float_as_uint(f);
    return (u + 0x7fffu + ((u >> 16) & 1u)) >> 16;
}
__device__ __forceinline__ float bf_lo(unsigned u) { return __uint_as_float(u << 16); }
__device__ __forceinline__ float bf_hi(unsigned u) { return __uint_as_float(u & 0xffff0000u); }

// Bijective XCD-chunked remap (m204): blocks on the same XCD get CONSECUTIVE
// work ids. bid%NXCD = xcd (dispatch round-robin), bid/NXCD = slot within xcd.
__device__ __forceinline__ int xcd_remap(int bid, int n) {
    int q = n / NXCD, r = n % NXCD;
    int xcd = bid % NXCD, slot = bid / NXCD;
    int base = (xcd < r) ? xcd * (q + 1) : r * (q + 1) + (xcd - r) * q;
    return base + slot;
}

// ---------------- K01: per-chunk bucket histogram + fused b cast ----------------
__global__ __launch_bounds__(1024) void k01_fused(
    const int* __restrict__ idx, const u32x4* __restrict__ b4,
    u32x4* __restrict__ bb4, unsigned short* __restrict__ cnt16,
    int* __restrict__ done, int E, int NBUX, int CH, int n8) {
    __shared__ int hist[NBMAX];
    int tid = threadIdx.x, c = blockIdx.x;
    int base = c * CH;
    int cnt  = min(CH, E - base);
    if (c == 0 && tid == 0) *done = 0;     // reset merged-scan counter each call
    for (int i = tid; i < NBUX; i += 1024) hist[i] = 0;
    __syncthreads();

    // int4-vectorized row histogram (base is 16B-aligned: CH % 4 == 0)
    int nv4 = cnt >> 2;
    const i32x4* rows4 = (const i32x4*)(idx + base);
    for (int i = tid; i < nv4; i += 1024) {
        i32x4 r = rows4[i];
        atomicAdd(&hist[r.x >> 6], 1);
        atomicAdd(&hist[r.y >> 6], 1);
        atomicAdd(&hist[r.z >> 6], 1);
        atomicAdd(&hist[r.w >> 6], 1);
    }
    for (int i = (nv4 << 2) + tid; i < cnt; i += 1024)
        atomicAdd(&hist[idx[base + i] >> 6], 1);
    __syncthreads();
    for (int i = tid; i < NBUX; i += 1024)
        cnt16[(size_t)c * NBUX + i] = (unsigned short)hist[i];

    // fused cast: whole-grid stride over b. NT loads: b f32 is single-touch;
    // keep Infinity Cache capacity for the bb table (16x reuse in K4).
    int gstride = gridDim.x * 1024;
    for (int i = blockIdx.x * 1024 + tid; i < n8; i += gstride) {
        u32x4 a = __builtin_nontemporal_load(b4 + 2 * i);
        u32x4 d = __builtin_nontemporal_load(b4 + 2 * i + 1);
        u32x4 o;
        o.x = bfr_rne(__uint_as_float(a.x)) | (bfr_rne(__uint_as_float(a.y)) << 16);
        o.y = bfr_rne(__uint_as_float(a.z)) | (bfr_rne(__uint_as_float(a.w)) << 16);
        o.z = bfr_rne(__uint_as_float(d.x)) | (bfr_rne(__uint_as_float(d.y)) << 16);
        o.w = bfr_rne(__uint_as_float(d.z)) | (bfr_rne(__uint_as_float(d.w)) << 16);
        bb4[i] = o;                        // normal store: bb must stay cached
    }
}

// ---------------- K2: per-bucket prefix + last-block scan (k2b folded in) ----------------
__global__ __launch_bounds__(256) void k2_merged(
    unsigned short* __restrict__ cnt16, int* __restrict__ total,
    int* __restrict__ boff, int* __restrict__ done, int NCHUNK, int NBUX) {
    __shared__ int s[256];
    __shared__ int lastflag;
    int tid  = threadIdx.x;
    int k    = blockIdx.x * 4 + (tid >> 6);
    int lane = tid & 63;

    if (k < NBUX) {
        int PC = (NCHUNK + 63) >> 6;       // chunks per lane, <= 8
        int c0 = lane * PC;
        int vals[8];
        int sum = 0;
#pragma unroll
        for (int j = 0; j < 8; ++j) {
            int c = c0 + j;
            vals[j] = (j < PC && c < NCHUNK) ? (int)cnt16[(size_t)c * NBUX + k] : 0;
            sum += vals[j];
        }
        int v = sum;
#pragma unroll
        for (int d = 1; d < 64; d <<= 1) {
            int t = __shfl_up(v, d, 64);
            if (lane >= d) v += t;
        }
        int run = v - sum;                 // exclusive prefix for this lane's chunks
#pragma unroll
        for (int j = 0; j < 8; ++j) {
            int c = c0 + j;
            if (j < PC && c < NCHUNK) {
                cnt16[(size_t)c * NBUX + k] = (unsigned short)run;
                run += vals[j];
            }
        }
        if (lane == 63) total[k] = run;
    }
    __syncthreads();

    // last-block-done: the final block performs the scan of totals -> boff
    if (tid == 0) {
        __threadfence();
        int old = atomicAdd(done, 1);
        lastflag = (old == (int)gridDim.x - 1);
    }
    __syncthreads();
    if (!lastflag) return;
    __threadfence();

    int n = NBUX;
    int loc[8]; int tot = 0;
#pragma unroll
    for (int j = 0; j < 8; ++j) { int i = tid * 8 + j; loc[j] = (i < n) ? total[i] : 0; tot += loc[j]; }
    s[tid] = tot; __syncthreads();
    for (int ofs = 1; ofs < 256; ofs <<= 1) {
        int v = (tid >= ofs) ? s[tid - ofs] : 0; __syncthreads();
        s[tid] += v; __syncthreads();
    }
    int run2 = s[tid] - tot;
#pragma unroll
    for (int j = 0; j < 8; ++j) { int i = tid * 8 + j; if (i < n) boff[i] = run2; run2 += loc[j]; }
    if (tid == 255) boff[n] = s[255];
}

// ---------------- K3: direct-to-slot scatter (XCD-chunked, vectorized) ----------------
__global__ __launch_bounds__(1024) void k3_scatter(
    const int* __restrict__ idx, const float* __restrict__ values,
    const unsigned short* __restrict__ lofs, const int* __restrict__ boff,
    int2* __restrict__ cv, int E, int NBUX, int CH, int NCHUNK, int colsAligned) {
    __shared__ int cur[NBMAX];
    int tid = threadIdx.x;
    int c   = xcd_remap(blockIdx.x, NCHUNK);   // same-XCD blocks -> consecutive chunks
    int base = c * CH;
    int cnt  = min(CH, E - base);
    for (int i = tid; i < NBUX; i += 1024)
        cur[i] = boff[i] + (int)lofs[(size_t)c * NBUX + i];
    __syncthreads();

    int nv4 = cnt >> 2;
    const i32x4* rows4 = (const i32x4*)(idx + base);
    const f32x4* vals4 = (const f32x4*)(values + base);
    const i32x4* cols4 = (const i32x4*)(idx + E + base);   // valid iff (E&3)==0
    for (int i = tid; i < nv4; i += 1024) {
        i32x4 r = rows4[i];
        f32x4 vv = __builtin_nontemporal_load(vals4 + i);  // single-touch
        i32x4 cl;
        if (colsAligned) {
            cl = __builtin_nontemporal_load(cols4 + i);    // single-touch
        } else {
            int e0 = base + (i << 2);
            cl.x = idx[E + e0]; cl.y = idx[E + e0 + 1];
            cl.z = idx[E + e0 + 2]; cl.w = idx[E + e0 + 3];
        }
        int pos;
        pos = atomicAdd(&cur[r.x >> 6], 1);
        cv[pos] = make_int2(((r.x & (RPB - 1)) << COLBITS) | cl.x, __float_as_int(vv.x));
        pos = atomicAdd(&cur[r.y >> 6], 1);
        cv[pos] = make_int2(((r.y & (RPB - 1)) << COLBITS) | cl.y, __float_as_int(vv.y));
        pos = atomicAdd(&cur[r.z >> 6], 1);
        cv[pos] = make_int2(((r.z & (RPB - 1)) << COLBITS) | cl.z, __float_as_int(vv.z));
        pos = atomicAdd(&cur[r.w >> 6], 1);
        cv[pos] = make_int2(((r.w & (RPB - 1)) << COLBITS) | cl.w, __float_as_int(vv.w));
    }
    for (int i = (nv4 << 2) + tid; i < cnt; i += 1024) {
        int   row = idx[base + i];
        int   col = idx[E + base + i];
        float v   = values[base + i];
        int pos = atomicAdd(&cur[row >> 6], 1);
        cv[pos] = make_int2(((row & (RPB - 1)) << COLBITS) | col, __float_as_int(v));
    }
}

// ---------------- K4: single-read reg-staged row-sort + bf16 gather ----------------
__global__ __launch_bounds__(256, 8) void k4_reg_bf16(
    const unsigned short* __restrict__ bb, const int2* __restrict__ cv,
    const int* __restrict__ boff, float* __restrict__ out, int N) {
    __shared__ int2 sorted[CAP];                 // 16 KB
    __shared__ int  rcnt[RPB], roff[RPB], rcur[RPB];

    int tid  = threadIdx.x;
    int lane = tid & 15;
    int grp  = tid >> 4;                         // 16 groups
    int k    = blockIdx.x;
    int s    = boff[k];
    int cnt  = min(boff[k + 1] - s, CAP);

    if (tid < RPB) rcnt[tid] = 0;

    // single coalesced cv read into registers (8 rec/thread), NT: read-once
    const unsigned long long* cv64 = (const unsigned long long*)cv;
    int2 rec[8];
#pragma unroll
    for (int j = 0; j < 8; ++j) {
        int i = tid + j * 256;
        if (i < cnt) {
            unsigned long long raw = __builtin_nontemporal_load(cv64 + s + i);
            rec[j].x = (int)(unsigned)(raw & 0xffffffffu);
            rec[j].y = (int)(unsigned)(raw >> 32);
        } else {
            rec[j] = make_int2(0, 0);
        }
    }
    __syncthreads();

    // pass A: row histogram from registers
#pragma unroll
    for (int j = 0; j < 8; ++j) {
        int i = tid + j * 256;
        if (i < cnt) atomicAdd(&rcnt[rec[j].x >> COLBITS], 1);
    }
    __syncthreads();

    // wave-scan 64 row counts
    if (tid < 64) {
        int cval = rcnt[tid];
        int v = cval;
#pragma unroll
        for (int d = 1; d < 64; d <<= 1) {
            int t = __shfl_up(v, d, 64);
            if (tid >= d) v += t;
        }
        roff[tid] = v - cval;
        rcur[tid] = v - cval;
    }
    __syncthreads();

    // pass B: counting-scatter registers -> sorted[]
#pragma unroll
    for (int j = 0; j < 8; ++j) {
        int i = tid + j * 256;
        if (i < cnt) {
            int pos = atomicAdd(&rcur[rec[j].x >> COLBITS], 1);
            sorted[pos] = rec[j];
        }
    }
    __syncthreads();

    float acc[4][8];
#pragma unroll
    for (int r = 0; r < 4; ++r)
#pragma unroll
        for (int j = 0; j < 8; ++j) acc[r][j] = 0.f;

    const unsigned short* bl = bb + (lane << 3);   // lane's 8 bf16 dims

#pragma unroll
    for (int r = 0; r < 4; ++r) {
        int lr = (grp << 2) | r;
        int i  = roff[lr];
        int re = rcur[lr];
        for (; i + 1 < re; i += 2) {
            int2 p0 = sorted[i];
            int2 p1 = sorted[i + 1];
            float v0 = __int_as_float(p0.y);
            float v1 = __int_as_float(p1.y);
            const uint4 w0 = *reinterpret_cast<const uint4*>(bl + ((size_t)(p0.x & COLMASK) << 7));
            const uint4 w1 = *reinterpret_cast<const uint4*>(bl + ((size_t)(p1.x & COLMASK) << 7));
            acc[r][0] += v0 * bf_lo(w0.x); acc[r][1] += v0 * bf_hi(w0.x);
            acc[r][2] += v0 * bf_lo(w0.y); acc[r][3] += v0 * bf_hi(w0.y);
            acc[r][4] += v0 * bf_lo(w0.z); acc[r][5] += v0 * bf_hi(w0.z);
            acc[r][6] += v0 * bf_lo(w0.w); acc[r][7] += v0 * bf_hi(w0.w);
            acc[r][0] += v1 * bf_lo(w1.x); acc[r][1] += v1 * bf_hi(w1.x);
            acc[r][2] += v1 * bf_lo(w1.y); acc[r][3] += v1 * bf_hi(w1.y);
            acc[r][4] += v1 * bf_lo(w1.z); acc[r][5] += v1 * bf_hi(w1.z);
            acc[r][6] += v1 * bf_lo(w1.w); acc[r][7] += v1 * bf_hi(w1.w);
        }
        if (i < re) {
            int2 p0 = sorted[i];
            float v0 = __int_as_float(p0.y);
            const uint4 w0 = *reinterpret_cast<const uint4*>(bl + ((size_t)(p0.x & COLMASK) << 7));
            acc[r][0] += v0 * bf_lo(w0.x); acc[r][1] += v0 * bf_hi(w0.x);
            acc[r][2] += v0 * bf_lo(w0.y); acc[r][3] += v0 * bf_hi(w0.y);
            acc[r][4] += v0 * bf_lo(w0.z); acc[r][5] += v0 * bf_hi(w0.z);
            acc[r][6] += v0 * bf_lo(w0.w); acc[r][7] += v0 * bf_hi(w0.w);
        }
    }

    // NT coalesced store (out is single-touch): 16 lanes x 32 B per row
#pragma unroll
    for (int r = 0; r < 4; ++r) {
        int row = (k << 6) + (grp << 2) + r;
        if (row < N) {
            float* po = out + ((size_t)row << 7) + (lane << 3);
            f32x4 o0 = {acc[r][0], acc[r][1], acc[r][2], acc[r][3]};
            f32x4 o1 = {acc[r][4], acc[r][5], acc[r][6], acc[r][7]};
            __builtin_nontemporal_store(o0, (f32x4*)po);
            __builtin_nontemporal_store(o1, (f32x4*)(po + 4));
        }
    }
}

// ---------------- tier-2: f32 gather ----------------
__global__ __launch_bounds__(256, 8) void k4_sortgather_f32(
    const float* __restrict__ b, const int2* __restrict__ cv,
    const int* __restrict__ boff, float* __restrict__ out, int N) {
    __shared__ int2 sorted[CAP];
    __shared__ int  rcnt[RPB], roff[RPB], rcur[RPB];
    int tid  = threadIdx.x;
    int lane = tid & 31;
    int grp  = tid >> 5;
    int k    = blockIdx.x;
    int s    = boff[k];
    int cnt  = min(boff[k + 1] - s, CAP);
    if (tid < RPB) rcnt[tid] = 0;
    __syncthreads();
    for (int i = tid; i < cnt; i += 256)
        atomicAdd(&rcnt[cv[s + i].x >> COLBITS], 1);
    __syncthreads();
    if (tid < 64) {
        int cval = rcnt[tid];
        int v = cval;
#pragma unroll
        for (int d = 1; d < 64; d <<= 1) {
            int t = __shfl_up(v, d, 64);
            if (tid >= d) v += t;
        }
        roff[tid] = v - cval;
        rcur[tid] = v - cval;
    }
    __syncthreads();
    for (int i = tid; i < cnt; i += 256) {
        int2 p = cv[s + i];
        int pos = atomicAdd(&rcur[p.x >> COLBITS], 1);
        sorted[pos] = p;
    }
    __syncthreads();
    float4 acc[8];
#pragma unroll
    for (int r = 0; r < 8; ++r) acc[r] = make_float4(0.f, 0.f, 0.f, 0.f);
    const float* bl = b + (lane << 2);
#pragma unroll
    for (int r = 0; r < 8; ++r) {
        int lr = (grp << 3) | r;
        int i  = roff[lr];
        int re = rcur[lr];
        for (; i < re; ++i) {
            int2 p0 = sorted[i];
            float v0 = __int_as_float(p0.y);
            const float4 b0 = *reinterpret_cast<const float4*>(bl + (size_t)(p0.x & COLMASK) * D_DIM);
            acc[r].x += v0 * b0.x; acc[r].y += v0 * b0.y;
            acc[r].z += v0 * b0.z; acc[r].w += v0 * b0.w;
        }
    }
#pragma unroll
    for (int r = 0; r < 8; ++r) {
        int row = (k << 6) + (grp << 3) + r;
        if (row < N)
            *reinterpret_cast<float4*>(out + (size_t)row * D_DIM + (lane << 2)) = acc[r];
    }
}

// ---------------- tier-3 fallback: atomic scatter ----------------
__global__ void spmm_atomic_scatter(const float* __restrict__ values,
                                    const float* __restrict__ b,
                                    const int* __restrict__ indices,
                                    float* __restrict__ out, int E) {
    long long gid = (long long)blockIdx.x * blockDim.x + threadIdx.x;
    long long total = (long long)E * 32;
    if (gid >= total) return;
    int e = (int)(gid >> 5);
    int c = (int)(gid & 31);
    int row = indices[e];
    int col = indices[E + e];
    float v = values[e];
    const float4 bv = *reinterpret_cast<const float4*>(b + (long long)col * D_DIM + (c << 2));
    float* o = out + (long long)row * D_DIM + (c << 2);
    atomicAdd(o + 0, v * bv.x);
    atomicAdd(o + 1, v * bv.y);
    atomicAdd(o + 2, v * bv.z);
    atomicAdd(o + 3, v * bv.w);
}

extern "C" void kernel_launch(void* const* d_in, const int* in_sizes, int n_in,
                              void* d_out, int out_size, void* d_ws, size_t ws_size,
                              hipStream_t stream) {
    const float* values = (const float*)d_in[0];
    const float* b      = (const float*)d_in[1];
    const int*   idx    = (const int*)d_in[2];
    float*       out    = (float*)d_out;

    const int E    = in_sizes[0];
    const int N    = out_size / D_DIM;
    const int NBUX = (N + RPB - 1) / RPB;

    size_t bb_bytes  = ((size_t)N * D_DIM * sizeof(unsigned short) + 15) & ~(size_t)15;
    // boff (NBUX+1) | total (NBUX) | done (1)  -- all i32, padded to 16B
    size_t int_bytes = (((size_t)(NBUX + 1) + NBUX + 4) * sizeof(int) + 15) & ~(size_t)15;
    size_t cv_bytes  = (size_t)E * sizeof(int2);

    int CH = 4096;
    int NCHUNK = (E + CH - 1) / CH;
    size_t c16_bytes = ((size_t)NCHUNK * NBUX * sizeof(unsigned short) + 15) & ~(size_t)15;
    size_t need1 = bb_bytes + int_bytes + c16_bytes + cv_bytes;
    if (ws_size < need1 || NCHUNK > NCMAX) {
        CH = 8192;
        NCHUNK = (E + CH - 1) / CH;
        c16_bytes = ((size_t)NCHUNK * NBUX * sizeof(unsigned short) + 15) & ~(size_t)15;
        need1 = bb_bytes + int_bytes + c16_bytes + cv_bytes;
    }
    size_t need2 = int_bytes + c16_bytes + cv_bytes;   // f32 tier (no bb)

    bool ok_shape = (NBUX <= NBMAX) && (NCHUNK <= NCMAX) && (N <= (1 << COLBITS)) &&
                    ((CH & 3) == 0);
    if (!ok_shape || ws_size < need2) {
        hipMemsetAsync(d_out, 0, (size_t)out_size * sizeof(float), stream);
        long long total = (long long)E * 32;
        int block = 256;
        long long grid = (total + block - 1) / block;
        spmm_atomic_scatter<<<(int)grid, block, 0, stream>>>(values, b, idx, out, E);
        return;
    }

    bool use_bf16 = (ws_size >= need1);
    char* base = (char*)d_ws;
    unsigned short* bb = (unsigned short*)base;
    if (use_bf16) base += bb_bytes;

    int*            boff  = (int*)base;
    int*            total = boff + (NBUX + 1);
    int*            done  = total + NBUX;
    unsigned short* cnt16 = (unsigned short*)(base + int_bytes);
    int2*           cv    = (int2*)(base + int_bytes + c16_bytes);

    int n8 = use_bf16 ? (N * D_DIM) / 8 : 0;
    int colsAligned = ((E & 3) == 0) ? 1 : 0;

    k01_fused<<<NCHUNK, 1024, 0, stream>>>(idx, (const u32x4*)b, (u32x4*)bb,
                                           cnt16, done, E, NBUX, CH, n8);
    k2_merged<<<(NBUX + 3) / 4, 256, 0, stream>>>(cnt16, total, boff, done, NCHUNK, NBUX);
    k3_scatter<<<NCHUNK, 1024, 0, stream>>>(idx, values, cnt16, boff, cv, E, NBUX,
                                            CH, NCHUNK, colsAligned);
    if (use_bf16)
        k4_reg_bf16<<<NBUX, 256, 0, stream>>>(bb, cv, boff, out, N);
    else
        k4_sortgather_f32<<<NBUX, 256, 0, stream>>>(b, cv, boff, out, N);
}

// Round 13
// 108.031 us; speedup vs baseline: 1.2496x; 1.2496x over previous
//
#include <hip/hip_runtime.h>

// SpecialSpmm: out[i] = sum_{e: row_e == i} values[e] * b[col_e]
// N = 100000, E = 1600000, D = 128.
//
// Pipeline (zero global atomics):  [Round-11 configuration — session best]
//   K01 k01_fused:    per CH-edge chunk: LDS bucket histogram -> cnt16[c][k],
//                     PLUS grid-strided f32->bf16 cast of b
//   K2a k2a_lofs:     wave-per-bucket prefix over chunks (cnt16 -> lofs) + totals
//   K2b k2b_scan:     one-block exclusive scan of totals -> boff
//   K3 k3_scatter:    per chunk: cur[k]=boff[k]+lofs[c][k], write records to
//                     final cv slot. XCD-aware chunk remap: consecutive chunks
//                     (adjacent slots of every bucket region) run on the SAME
//                     XCD so cv lines fill within one L2 (no cross-XCD pingpong).
//   K4 k4_reg_bf16:   per bucket: cv segment read ONCE into registers,
//                     LDS hist from regs, wave-scan, reg->LDS counting scatter,
//                     bf16 register gather (16 grp x 4 rows x bf16x8/lane).
//
// d_in[0] = values (E f32), d_in[1] = b (N*D f32),
// d_in[2] = indices (2*E i32: rows then cols), d_in[3] = n (1 i32).

#define D_DIM    128
#define RPB      64                    // rows per bucket
#define COLBITS  17                    // N <= 131072
#define COLMASK  ((1 << COLBITS) - 1)
#define NCMAX    512                   // max chunks supported by k2a (8/lane)
#define NBMAX    1600                  // max buckets (N <= 102400)
#define CAP      2048                  // LDS sorted capacity (records)
#define NXCD     8

__device__ __forceinline__ unsigned bfr_rne(float f) {
    unsigned u = __float_as_uint(f);
    return (u + 0x7fffu + ((u >> 16) & 1u)) >> 16;
}
__device__ __forceinline__ float bf_lo(unsigned u) { return __uint_as_float(u << 16); }
__device__ __forceinline__ float bf_hi(unsigned u) { return __uint_as_float(u & 0xffff0000u); }

// Bijective XCD-chunked remap (m204): blocks on the same XCD get CONSECUTIVE
// work ids. bid%NXCD = xcd (dispatch round-robin), bid/NXCD = slot within xcd.
__device__ __forceinline__ int xcd_remap(int bid, int n) {
    int q = n / NXCD, r = n % NXCD;
    int xcd = bid % NXCD, slot = bid / NXCD;
    int base = (xcd < r) ? xcd * (q + 1) : r * (q + 1) + (xcd - r) * q;
    return base + slot;
}

// ---------------- K01: per-chunk bucket histogram + fused b cast ----------------
__global__ __launch_bounds__(1024) void k01_fused(
    const int* __restrict__ idx, const float4* __restrict__ b4,
    uint4* __restrict__ bb4, unsigned short* __restrict__ cnt16,
    int E, int NBUX, int CH, int n8) {
    __shared__ int hist[NBMAX];
    int tid = threadIdx.x, c = blockIdx.x;
    int base = c * CH;
    int cnt  = min(CH, E - base);
    for (int i = tid; i < NBUX; i += 1024) hist[i] = 0;
    __syncthreads();
    for (int i = tid; i < cnt; i += 1024)
        atomicAdd(&hist[idx[base + i] >> 6], 1);
    __syncthreads();
    for (int i = tid; i < NBUX; i += 1024)
        cnt16[(size_t)c * NBUX + i] = (unsigned short)hist[i];

    // fused cast: whole-grid stride over b (independent of histogram)
    int gstride = gridDim.x * 1024;
    for (int i = blockIdx.x * 1024 + tid; i < n8; i += gstride) {
        float4 a = b4[2 * i];
        float4 d = b4[2 * i + 1];
        uint4 o;
        o.x = bfr_rne(a.x) | (bfr_rne(a.y) << 16);
        o.y = bfr_rne(a.z) | (bfr_rne(a.w) << 16);
        o.z = bfr_rne(d.x) | (bfr_rne(d.y) << 16);
        o.w = bfr_rne(d.z) | (bfr_rne(d.w) << 16);
        bb4[i] = o;
    }
}

// ---------------- K2a: wave-per-bucket prefix over chunks (<=512) ----------------
__global__ __launch_bounds__(256) void k2a_lofs(
    unsigned short* __restrict__ cnt16, int* __restrict__ total,
    int NCHUNK, int NBUX) {
    int k    = blockIdx.x * 4 + (threadIdx.x >> 6);
    int lane = threadIdx.x & 63;
    if (k >= NBUX) return;
    int PC = (NCHUNK + 63) >> 6;       // chunks per lane, <= 8
    int c0 = lane * PC;
    int vals[8];
    int sum = 0;
#pragma unroll
    for (int j = 0; j < 8; ++j) {
        int c = c0 + j;
        vals[j] = (j < PC && c < NCHUNK) ? (int)cnt16[(size_t)c * NBUX + k] : 0;
        sum += vals[j];
    }
    int v = sum;
#pragma unroll
    for (int d = 1; d < 64; d <<= 1) {
        int t = __shfl_up(v, d, 64);
        if (lane >= d) v += t;
    }
    int run = v - sum;                 // exclusive prefix for this lane's chunks
#pragma unroll
    for (int j = 0; j < 8; ++j) {
        int c = c0 + j;
        if (j < PC && c < NCHUNK) {
            cnt16[(size_t)c * NBUX + k] = (unsigned short)run;
            run += vals[j];
        }
    }
    if (lane == 63) total[k] = run;
}

// ---------------- K2b: one-block exclusive scan (n <= 2048) ----------------
__global__ void k2b_scan(const int* __restrict__ total, int* __restrict__ boff, int n) {
    __shared__ int s[256];
    int t = threadIdx.x;
    int loc[8]; int tot = 0;
#pragma unroll
    for (int j = 0; j < 8; ++j) { int i = t * 8 + j; loc[j] = (i < n) ? total[i] : 0; tot += loc[j]; }
    s[t] = tot; __syncthreads();
    for (int ofs = 1; ofs < 256; ofs <<= 1) {
        int v = (t >= ofs) ? s[t - ofs] : 0; __syncthreads();
        s[t] += v; __syncthreads();
    }
    int run = s[t] - tot;
#pragma unroll
    for (int j = 0; j < 8; ++j) { int i = t * 8 + j; if (i < n) boff[i] = run; run += loc[j]; }
    if (t == 255) boff[n] = s[255];
}

// ---------------- K3: direct-to-slot scatter (XCD-chunked) ----------------
__global__ __launch_bounds__(1024) void k3_scatter(
    const int* __restrict__ idx, const float* __restrict__ values,
    const unsigned short* __restrict__ lofs, const int* __restrict__ boff,
    int2* __restrict__ cv, int E, int NBUX, int CH, int NCHUNK) {
    __shared__ int cur[NBMAX];
    int tid = threadIdx.x;
    int c   = xcd_remap(blockIdx.x, NCHUNK);   // same-XCD blocks -> consecutive chunks
    int base = c * CH;
    int cnt  = min(CH, E - base);
    for (int i = tid; i < NBUX; i += 1024)
        cur[i] = boff[i] + (int)lofs[(size_t)c * NBUX + i];
    __syncthreads();
    for (int i = tid; i < cnt; i += 1024) {
        int   row = idx[base + i];
        int   col = idx[E + base + i];
        float v   = values[base + i];
        int pos = atomicAdd(&cur[row >> 6], 1);
        cv[pos] = make_int2(((row & (RPB - 1)) << COLBITS) | col, __float_as_int(v));
    }
}

// ---------------- K4: single-read reg-staged row-sort + bf16 gather ----------------
__global__ __launch_bounds__(256, 8) void k4_reg_bf16(
    const unsigned short* __restrict__ bb, const int2* __restrict__ cv,
    const int* __restrict__ boff, float* __restrict__ out, int N) {
    __shared__ int2 sorted[CAP];                 // 16 KB
    __shared__ int  rcnt[RPB], roff[RPB], rcur[RPB];

    int tid  = threadIdx.x;
    int lane = tid & 15;
    int grp  = tid >> 4;                         // 16 groups
    int k    = blockIdx.x;
    int s    = boff[k];
    int cnt  = min(boff[k + 1] - s, CAP);

    if (tid < RPB) rcnt[tid] = 0;

    // single coalesced cv read into registers (8 rec/thread, fully unrolled)
    int2 rec[8];
#pragma unroll
    for (int j = 0; j < 8; ++j) {
        int i = tid + j * 256;
        rec[j] = (i < cnt) ? cv[s + i] : make_int2(0, 0);
    }
    __syncthreads();

    // pass A: row histogram from registers
#pragma unroll
    for (int j = 0; j < 8; ++j) {
        int i = tid + j * 256;
        if (i < cnt) atomicAdd(&rcnt[rec[j].x >> COLBITS], 1);
    }
    __syncthreads();

    // wave-scan 64 row counts
    if (tid < 64) {
        int cval = rcnt[tid];
        int v = cval;
#pragma unroll
        for (int d = 1; d < 64; d <<= 1) {
            int t = __shfl_up(v, d, 64);
            if (tid >= d) v += t;
        }
        roff[tid] = v - cval;
        rcur[tid] = v - cval;
    }
    __syncthreads();

    // pass B: counting-scatter registers -> sorted[]
#pragma unroll
    for (int j = 0; j < 8; ++j) {
        int i = tid + j * 256;
        if (i < cnt) {
            int pos = atomicAdd(&rcur[rec[j].x >> COLBITS], 1);
            sorted[pos] = rec[j];
        }
    }
    __syncthreads();

    float acc[4][8];
#pragma unroll
    for (int r = 0; r < 4; ++r)
#pragma unroll
        for (int j = 0; j < 8; ++j) acc[r][j] = 0.f;

    const unsigned short* bl = bb + (lane << 3);   // lane's 8 bf16 dims

#pragma unroll
    for (int r = 0; r < 4; ++r) {
        int lr = (grp << 2) | r;
        int i  = roff[lr];
        int re = rcur[lr];
        for (; i + 1 < re; i += 2) {
            int2 p0 = sorted[i];
            int2 p1 = sorted[i + 1];
            float v0 = __int_as_float(p0.y);
            float v1 = __int_as_float(p1.y);
            const uint4 w0 = *reinterpret_cast<const uint4*>(bl + ((size_t)(p0.x & COLMASK) << 7));
            const uint4 w1 = *reinterpret_cast<const uint4*>(bl + ((size_t)(p1.x & COLMASK) << 7));
            acc[r][0] += v0 * bf_lo(w0.x); acc[r][1] += v0 * bf_hi(w0.x);
            acc[r][2] += v0 * bf_lo(w0.y); acc[r][3] += v0 * bf_hi(w0.y);
            acc[r][4] += v0 * bf_lo(w0.z); acc[r][5] += v0 * bf_hi(w0.z);
            acc[r][6] += v0 * bf_lo(w0.w); acc[r][7] += v0 * bf_hi(w0.w);
            acc[r][0] += v1 * bf_lo(w1.x); acc[r][1] += v1 * bf_hi(w1.x);
            acc[r][2] += v1 * bf_lo(w1.y); acc[r][3] += v1 * bf_hi(w1.y);
            acc[r][4] += v1 * bf_lo(w1.z); acc[r][5] += v1 * bf_hi(w1.z);
            acc[r][6] += v1 * bf_lo(w1.w); acc[r][7] += v1 * bf_hi(w1.w);
        }
        if (i < re) {
            int2 p0 = sorted[i];
            float v0 = __int_as_float(p0.y);
            const uint4 w0 = *reinterpret_cast<const uint4*>(bl + ((size_t)(p0.x & COLMASK) << 7));
            acc[r][0] += v0 * bf_lo(w0.x); acc[r][1] += v0 * bf_hi(w0.x);
            acc[r][2] += v0 * bf_lo(w0.y); acc[r][3] += v0 * bf_hi(w0.y);
            acc[r][4] += v0 * bf_lo(w0.z); acc[r][5] += v0 * bf_hi(w0.z);
            acc[r][6] += v0 * bf_lo(w0.w); acc[r][7] += v0 * bf_hi(w0.w);
        }
    }

    // coalesced store: 16 lanes x 32 B per row (also zeros empty rows)
#pragma unroll
    for (int r = 0; r < 4; ++r) {
        int row = (k << 6) + (grp << 2) + r;
        if (row < N) {
            float* po = out + ((size_t)row << 7) + (lane << 3);
            *reinterpret_cast<float4*>(po)     = make_float4(acc[r][0], acc[r][1], acc[r][2], acc[r][3]);
            *reinterpret_cast<float4*>(po + 4) = make_float4(acc[r][4], acc[r][5], acc[r][6], acc[r][7]);
        }
    }
}

// ---------------- tier-2: f32 gather ----------------
__global__ __launch_bounds__(256, 8) void k4_sortgather_f32(
    const float* __restrict__ b, const int2* __restrict__ cv,
    const int* __restrict__ boff, float* __restrict__ out, int N) {
    __shared__ int2 sorted[CAP];
    __shared__ int  rcnt[RPB], roff[RPB], rcur[RPB];
    int tid  = threadIdx.x;
    int lane = tid & 31;
    int grp  = tid >> 5;
    int k    = blockIdx.x;
    int s    = boff[k];
    int cnt  = min(boff[k + 1] - s, CAP);
    if (tid < RPB) rcnt[tid] = 0;
    __syncthreads();
    for (int i = tid; i < cnt; i += 256)
        atomicAdd(&rcnt[cv[s + i].x >> COLBITS], 1);
    __syncthreads();
    if (tid < 64) {
        int cval = rcnt[tid];
        int v = cval;
#pragma unroll
        for (int d = 1; d < 64; d <<= 1) {
            int t = __shfl_up(v, d, 64);
            if (tid >= d) v += t;
        }
        roff[tid] = v - cval;
        rcur[tid] = v - cval;
    }
    __syncthreads();
    for (int i = tid; i < cnt; i += 256) {
        int2 p = cv[s + i];
        int pos = atomicAdd(&rcur[p.x >> COLBITS], 1);
        sorted[pos] = p;
    }
    __syncthreads();
    float4 acc[8];
#pragma unroll
    for (int r = 0; r < 8; ++r) acc[r] = make_float4(0.f, 0.f, 0.f, 0.f);
    const float* bl = b + (lane << 2);
#pragma unroll
    for (int r = 0; r < 8; ++r) {
        int lr = (grp << 3) | r;
        int i  = roff[lr];
        int re = rcur[lr];
        for (; i < re; ++i) {
            int2 p0 = sorted[i];
            float v0 = __int_as_float(p0.y);
            const float4 b0 = *reinterpret_cast<const float4*>(bl + (size_t)(p0.x & COLMASK) * D_DIM);
            acc[r].x += v0 * b0.x; acc[r].y += v0 * b0.y;
            acc[r].z += v0 * b0.z; acc[r].w += v0 * b0.w;
        }
    }
#pragma unroll
    for (int r = 0; r < 8; ++r) {
        int row = (k << 6) + (grp << 3) + r;
        if (row < N)
            *reinterpret_cast<float4*>(out + (size_t)row * D_DIM + (lane << 2)) = acc[r];
    }
}

// ---------------- tier-3 fallback: atomic scatter ----------------
__global__ void spmm_atomic_scatter(const float* __restrict__ values,
                                    const float* __restrict__ b,
                                    const int* __restrict__ indices,
                                    float* __restrict__ out, int E) {
    long long gid = (long long)blockIdx.x * blockDim.x + threadIdx.x;
    long long total = (long long)E * 32;
    if (gid >= total) return;
    int e = (int)(gid >> 5);
    int c = (int)(gid & 31);
    int row = indices[e];
    int col = indices[E + e];
    float v = values[e];
    const float4 bv = *reinterpret_cast<const float4*>(b + (long long)col * D_DIM + (c << 2));
    float* o = out + (long long)row * D_DIM + (c << 2);
    atomicAdd(o + 0, v * bv.x);
    atomicAdd(o + 1, v * bv.y);
    atomicAdd(o + 2, v * bv.z);
    atomicAdd(o + 3, v * bv.w);
}

extern "C" void kernel_launch(void* const* d_in, const int* in_sizes, int n_in,
                              void* d_out, int out_size, void* d_ws, size_t ws_size,
                              hipStream_t stream) {
    const float* values = (const float*)d_in[0];
    const float* b      = (const float*)d_in[1];
    const int*   idx    = (const int*)d_in[2];
    float*       out    = (float*)d_out;

    const int E    = in_sizes[0];
    const int N    = out_size / D_DIM;
    const int NBUX = (N + RPB - 1) / RPB;

    size_t bb_bytes  = ((size_t)N * D_DIM * sizeof(unsigned short) + 15) & ~(size_t)15;
    size_t int_bytes = (((size_t)(NBUX + 1) + NBUX) * sizeof(int) + 15) & ~(size_t)15;
    size_t cv_bytes  = (size_t)E * sizeof(int2);

    int CH = 4096;
    int NCHUNK = (E + CH - 1) / CH;
    size_t c16_bytes = ((size_t)NCHUNK * NBUX * sizeof(unsigned short) + 15) & ~(size_t)15;
    size_t need1 = bb_bytes + int_bytes + c16_bytes + cv_bytes;
    if (ws_size < need1 || NCHUNK > NCMAX) {
        CH = 8192;
        NCHUNK = (E + CH - 1) / CH;
        c16_bytes = ((size_t)NCHUNK * NBUX * sizeof(unsigned short) + 15) & ~(size_t)15;
        need1 = bb_bytes + int_bytes + c16_bytes + cv_bytes;
    }
    size_t need2 = int_bytes + c16_bytes + cv_bytes;   // f32 tier (no bb)

    bool ok_shape = (NBUX <= NBMAX) && (NCHUNK <= NCMAX) && (N <= (1 << COLBITS));
    if (!ok_shape || ws_size < need2) {
        hipMemsetAsync(d_out, 0, (size_t)out_size * sizeof(float), stream);
        long long total = (long long)E * 32;
        int block = 256;
        long long grid = (total + block - 1) / block;
        spmm_atomic_scatter<<<(int)grid, block, 0, stream>>>(values, b, idx, out, E);
        return;
    }

    bool use_bf16 = (ws_size >= need1);
    char* base = (char*)d_ws;
    unsigned short* bb = (unsigned short*)base;
    if (use_bf16) base += bb_bytes;

    int*            boff  = (int*)base;
    int*            total = boff + (NBUX + 1);
    unsigned short* cnt16 = (unsigned short*)(base + int_bytes);
    int2*           cv    = (int2*)(base + int_bytes + c16_bytes);

    int n8 = use_bf16 ? (N * D_DIM) / 8 : 0;
    k01_fused<<<NCHUNK, 1024, 0, stream>>>(idx, (const float4*)b, (uint4*)bb,
                                           cnt16, E, NBUX, CH, n8);
    k2a_lofs<<<(NBUX + 3) / 4, 256, 0, stream>>>(cnt16, total, NCHUNK, NBUX);
    k2b_scan<<<1, 256, 0, stream>>>(total, boff, NBUX);
    k3_scatter<<<NCHUNK, 1024, 0, stream>>>(idx, values, cnt16, boff, cv, E, NBUX, CH, NCHUNK);
    if (use_bf16)
        k4_reg_bf16<<<NBUX, 256, 0, stream>>>(bb, cv, boff, out, N);
    else
        k4_sortgather_f32<<<NBUX, 256, 0, stream>>>(b, cv, boff, out, N);
}